// Round 1
// 438.980 us; speedup vs baseline: 1.0052x; 1.0052x over previous
//
#include <hip/hip_runtime.h>

#define SLEN 2048
#define BATCH 32
#define HDIM 512
#define KDIM 1024   // 2H

typedef _Float16 f16x8 __attribute__((ext_vector_type(8)));
typedef _Float16 f16x4 __attribute__((ext_vector_type(4)));
typedef float f32x4 __attribute__((ext_vector_type(4)));

__device__ __forceinline__ void gload16(const void* g, void* l) {
  __builtin_amdgcn_global_load_lds(
      (const __attribute__((address_space(1))) unsigned int*)g,
      (__attribute__((address_space(3))) unsigned int*)l, 16, 0, 0);
}

__device__ __forceinline__ float fast_tanh(float x) {
  float e = __expf(2.0f * x);
  return 1.0f - 2.0f * __builtin_amdgcn_rcpf(e + 1.0f);
}

// ---- prep: [0,512) W2->f16 | [512,4608) s1 | [4608,4640) zero score ----
__global__ __launch_bounds__(256) void prep_k(const float* __restrict__ attn_w,
                                              const float* __restrict__ attn_b,
                                              const float* __restrict__ hidden,
                                              _Float16* __restrict__ Bt,
                                              float* __restrict__ s1,
                                              float* __restrict__ score) {
  if (blockIdx.x < 512) {
    int t = blockIdx.x * 256 + threadIdx.x;
    int h = t >> 8;
    int c = t & 255;
    float4 x = *(const float4*)(attn_w + (size_t)h * 2048 + 1024 + c * 4);
    f16x4 y = {(_Float16)x.x, (_Float16)x.y, (_Float16)x.z, (_Float16)x.w};
    *(f16x4*)(Bt + (size_t)h * 1024 + c * 4) = y;
  } else if (blockIdx.x < 4608) {
    int o = (blockIdx.x - 512) * 4 + (threadIdx.x >> 6);  // one wave per output
    int b = o >> 9, h = o & 511;
    int lane = threadIdx.x & 63;
    const float4* hp = (const float4*)(hidden + (size_t)b * 1024);
    const float4* wp = (const float4*)(attn_w + (size_t)h * 2048);
    float acc = 0.f;
#pragma unroll
    for (int c = 0; c < 4; ++c) {
      float4 a = hp[c * 64 + lane];
      float4 wv = wp[c * 64 + lane];
      acc += a.x * wv.x + a.y * wv.y + a.z * wv.z + a.w * wv.w;
    }
#pragma unroll
    for (int off = 1; off < 64; off <<= 1) acc += __shfl_xor(acc, off);
    if (lane == 0) s1[o] = acc + attn_b[h];
  } else {
    int idx = (blockIdx.x - 4608) * 256 + threadIdx.x;
    float4 z = {0.f, 0.f, 0.f, 0.f};
    ((float4*)score)[idx] = z;
    ((float4*)score)[idx + 8192] = z;
  }
}

// ---- Main fused GEMM: BM=256, BN=128, BK=32; double-buffered prefetch ----
// As[2][256][32] fp32, XOR-swizzled: phys 16B-chunk p of row r = logical c ^ (r&7)
// Bs[2][128][32] f16,  XOR-swizzled: phys 16B-chunk p of row r = logical c ^ ((r>>2)&3)
// Pipeline (T3): stage(t+1) issued BEFORE compute(t); __syncthreads at loop top
// drains loads that had a full MFMA phase in flight.
__global__ __launch_bounds__(256, 2) void gemm_k(const float* __restrict__ eo,
                                                 const _Float16* __restrict__ Bt,
                                                 const float* __restrict__ s1,
                                                 const float* __restrict__ v,
                                                 float* __restrict__ score) {
  constexpr int BK = 32;
  constexpr int NKT = KDIM / BK;                      // 32
  __shared__ __align__(16) float As[2][256 * BK];     // 2 x 32 KB
  __shared__ __align__(16) _Float16 Bs[2][128 * BK];  // 2 x 8 KB

  int bid = blockIdx.x;
  // XCD swizzle: the 4 n-tiles of one m-tile land on one XCD (share A in its L2)
  int x = bid & 7;
  int q = bid >> 3;
  int nt = q & 3;
  int mt = (q >> 2) * 8 + x;           // 0..255

  int tid = threadIdx.x;
  int lane = tid & 63;
  int w = tid >> 6;
  int wm = w * 64;                     // wave owns rows wm..wm+63, all 128 n

  // Pre-swizzled global source pointers (gload_lds writes linearly: lane l ->
  // dest base + 16*l, so the source address carries the chunk permutation).
  // A issue i: rows 64w+8i..+8, lane l -> (row 64w+8i+(l>>3), phys chunk l&7),
  //            source logical chunk = (l&7) ^ (l>>3)   [= p ^ (r&7)]
  // B issue i: rows 32w+16i..+16, lane l -> (row +(l>>2), phys chunk l&3),
  //            source logical chunk = (l&3) ^ (l>>4)   [= p ^ ((r>>2)&3)]
  const float* ga[8];
  const _Float16* gb[2];
#pragma unroll
  for (int i = 0; i < 8; ++i)
    ga[i] = eo + (size_t)(mt * 256 + 64 * w + 8 * i + (lane >> 3)) * KDIM
              + (((lane & 7) ^ (lane >> 3)) << 2);
  gb[0] = Bt + (size_t)(nt * 128 + 32 * w + (lane >> 2)) * KDIM
            + (((lane & 3) ^ (lane >> 4)) << 3);
  gb[1] = gb[0] + 16 * KDIM;

  f32x4 acc[4][8];
#pragma unroll
  for (int i = 0; i < 4; ++i)
#pragma unroll
    for (int j = 0; j < 8; ++j) acc[i][j] = (f32x4){0.f, 0.f, 0.f, 0.f};

  int mrow = lane & 15;
  int quad = lane >> 4;
  int bchunk = (quad ^ (mrow >> 2)) & 3;   // B read phys chunk
  int as_sw = mrow & 7;                    // A read row-swizzle key

  // ---- prologue: stage kt=0 into buffer 0 ----
  {
    gload16(gb[0], (char*)Bs[0] + (w * 2 + 0) * 1024);
    gload16(gb[1], (char*)Bs[0] + (w * 2 + 1) * 1024);
    gb[0] += BK; gb[1] += BK;
#pragma unroll
    for (int i = 0; i < 8; ++i) {
      gload16(ga[i], (char*)As[0] + (w * 8 + i) * 1024);
      ga[i] += BK;
    }
  }

  for (int kt = 0; kt < NKT; ++kt) {
    int cur = kt & 1;
    __syncthreads();    // vmcnt(0)+barrier: buf[cur] staged; buf[cur^1] free

    if (kt + 1 < NKT) {  // issue next tile into buf[cur^1] (flies under MFMA)
      gload16(gb[0], (char*)Bs[cur ^ 1] + (w * 2 + 0) * 1024);
      gload16(gb[1], (char*)Bs[cur ^ 1] + (w * 2 + 1) * 1024);
      gb[0] += BK; gb[1] += BK;
#pragma unroll
      for (int i = 0; i < 8; ++i) {
        gload16(ga[i], (char*)As[cur ^ 1] + (w * 8 + i) * 1024);
        ga[i] += BK;
      }
    }

    const float* Ab = As[cur];
    const _Float16* Bb = Bs[cur];
    f16x8 bf[8], af[4];
#pragma unroll
    for (int j = 0; j < 8; ++j)
      bf[j] = *(const f16x8*)&Bb[(16 * j + mrow) * BK + (bchunk << 3)];
#pragma unroll
    for (int i = 0; i < 4; ++i) {
      const float* pa = &Ab[(wm + 16 * i + mrow) * BK];
      float4 a0 = *(const float4*)(pa + (((2 * quad) ^ as_sw) << 2));
      float4 a1 = *(const float4*)(pa + (((2 * quad + 1) ^ as_sw) << 2));
      f16x8 t = {(_Float16)a0.x, (_Float16)a0.y, (_Float16)a0.z, (_Float16)a0.w,
                 (_Float16)a1.x, (_Float16)a1.y, (_Float16)a1.z, (_Float16)a1.w};
      af[i] = t;
    }
    __builtin_amdgcn_s_setprio(1);
#pragma unroll
    for (int i = 0; i < 4; ++i)
#pragma unroll
      for (int j = 0; j < 8; ++j)
        acc[i][j] = __builtin_amdgcn_mfma_f32_16x16x32_f16(af[i], bf[j], acc[i][j], 0, 0, 0);
    __builtin_amdgcn_s_setprio(0);
  }

  // ---- Epilogue: energy = tanh(acc + s1[b][h]); score += energy * v[h] ----
  __syncthreads();
  float* s1s = (float*)As;            // [32][132] fp32 (stride-132: conflict-free)
  float* vsm = (float*)Bs;            // [128] fp32
  for (int t = tid; t < 1024; t += 256) {
    int bb = t >> 5, cc = t & 31;
    ((float4*)s1s)[bb * 33 + cc] = *(const float4*)(s1 + (size_t)bb * 512 + nt * 128 + cc * 4);
  }
  if (tid < 32) ((float4*)vsm)[tid] = *(const float4*)(v + nt * 128 + tid * 4);
  __syncthreads();

  int lcol = lane & 15;
  float vv[8];
#pragma unroll
  for (int j = 0; j < 8; ++j) vv[j] = vsm[16 * j + lcol];

#pragma unroll
  for (int i = 0; i < 4; ++i) {
#pragma unroll
    for (int r = 0; r < 4; ++r) {
      int mloc = wm + 16 * i + 4 * quad + r;
      int bb = mloc & 31;   // mt*256 ≡ 0 (mod 32)
      float sum = 0.f;
#pragma unroll
      for (int j = 0; j < 8; ++j) {
        float e = acc[i][j][r] + s1s[bb * 132 + 16 * j + lcol];
        sum += fast_tanh(e) * vv[j];
      }
      sum += __shfl_xor(sum, 1);
      sum += __shfl_xor(sum, 2);
      sum += __shfl_xor(sum, 4);
      sum += __shfl_xor(sum, 8);
      if (lcol == 0) {
        int mg = mt * 256 + mloc;        // global row m = s*32 + b
        atomicAdd(&score[(mg & 31) * SLEN + (mg >> 5)], sum);
      }
    }
  }
}

// ---- Masked softmax over s for each b; score stored b-major [32][2048] ----
__global__ __launch_bounds__(256) void softmax_k(const float* __restrict__ score,
                                                 const int* __restrict__ mask,
                                                 float* __restrict__ out) {
  int b = blockIdx.x;
  int tid = threadIdx.x;
  int lane = tid & 63, w = tid >> 6;
  __shared__ float red[8];
  float vals[8];
  float mx = -3.4e38f;
#pragma unroll
  for (int i = 0; i < 8; ++i) {
    int s = i * 256 + tid;
    float xv = score[b * SLEN + s];
    if (mask[b * SLEN + s] == 0) xv = -1e10f;
    vals[i] = xv;
    mx = fmaxf(mx, xv);
  }
#pragma unroll
  for (int off = 1; off < 64; off <<= 1) mx = fmaxf(mx, __shfl_xor(mx, off));
  if (lane == 0) red[w] = mx;
  __syncthreads();
  mx = fmaxf(fmaxf(red[0], red[1]), fmaxf(red[2], red[3]));
  float sum = 0.f;
#pragma unroll
  for (int i = 0; i < 8; ++i) {
    vals[i] = __expf(vals[i] - mx);
    sum += vals[i];
  }
#pragma unroll
  for (int off = 1; off < 64; off <<= 1) sum += __shfl_xor(sum, off);
  if (lane == 0) red[4 + w] = sum;
  __syncthreads();
  sum = red[4] + red[5] + red[6] + red[7];
  float inv = 1.0f / sum;
#pragma unroll
  for (int i = 0; i < 8; ++i) out[b * SLEN + i * 256 + tid] = vals[i] * inv;
}

extern "C" void kernel_launch(void* const* d_in, const int* in_sizes, int n_in,
                              void* d_out, int out_size, void* d_ws, size_t ws_size,
                              hipStream_t stream) {
  const float* hidden = (const float*)d_in[0];
  const float* eo     = (const float*)d_in[1];
  const int*   mask   = (const int*)d_in[2];
  const float* attn_w = (const float*)d_in[3];
  const float* attn_b = (const float*)d_in[4];
  const float* v      = (const float*)d_in[5];
  float* out = (float*)d_out;

  char* wsb = (char*)d_ws;
  _Float16* Bt = (_Float16*)wsb;                              // 1 MB
  float* s1    = (float*)(wsb + (1 << 20));                   // 64 KB
  float* score = (float*)(wsb + (1 << 20) + (1 << 16));       // 256 KB

  prep_k<<<4640, 256, 0, stream>>>(attn_w, attn_b, hidden, Bt, s1, score);
  gemm_k<<<1024, 256, 0, stream>>>(eo, Bt, s1, v, score);
  softmax_k<<<BATCH, 256, 0, stream>>>(score, mask, out);
}